// Round 3
// baseline (266.209 us; speedup 1.0000x reference)
//
#include <hip/hip_runtime.h>
#include <math.h>

// Problem constants (from reference)
#define NNB 16   // neighbors
#define NOB 8    // obstacles
#define SDIM 4   // state dim
#define H1D 64   // hidden 1
#define ED 16    // embedding
#define HPD 64   // psi hidden
#define XW (1 + SDIM + SDIM*NNB + 2*NOB)  // 85 floats per row

#define NNB_H (NNB/2)  // neighbors per half-thread
#define NOB_H (NOB/2)  // obstacles per half-thread

__device__ __forceinline__ float fast_rcp(float x) { return __builtin_amdgcn_rcpf(x); }
__device__ __forceinline__ float fast_sqrt(float x) { return __builtin_amdgcn_sqrtf(x); }

// 2*tanh(a), overflow-safe, ~1e-6 rel err (output compared at bf16 granularity)
__device__ __forceinline__ float two_tanh(float a) {
    float ax = fabsf(a);
    float e = __expf(2.0f * ax);
    float t = 1.0f - 2.0f * fast_rcp(e + 1.0f);
    return copysignf(2.0f * t, a);
}

// Two threads (lane pair 2i, 2i+1) cooperate on one row:
//  - each half does 8 neighbors + 4 obstacles of the phi/barrier sums
//  - combine via __shfl_xor(.,1)
//  - rho / psi tail duplicated in both halves (keeps weight loads wave-uniform
//    scalar; tail is only ~30% of the FLOPs)
__global__ __launch_bounds__(256) void barrier_net_kernel(
    const float* __restrict__ x,
    const float* __restrict__ Wp1n, const float* __restrict__ bp1n,
    const float* __restrict__ Wp2n, const float* __restrict__ bp2n,
    const float* __restrict__ Wr1n, const float* __restrict__ br1n,
    const float* __restrict__ Wr2n, const float* __restrict__ br2n,
    const float* __restrict__ Wp1o, const float* __restrict__ bp1o,
    const float* __restrict__ Wp2o, const float* __restrict__ bp2o,
    const float* __restrict__ Wr1o, const float* __restrict__ br1o,
    const float* __restrict__ Wr2o, const float* __restrict__ br2o,
    const float* __restrict__ Wpsi1, const float* __restrict__ bpsi1,
    const float* __restrict__ Wpsi2, const float* __restrict__ bpsi2,
    float* __restrict__ out, int nb)
{
    int t = blockIdx.x * blockDim.x + threadIdx.x;
    int row = t >> 1;
    if (row >= nb) return;
    int half = t & 1;
    const float* xr = x + (size_t)row * XW;

    // goal vector (needed by both halves for the duplicated psi tail)
    float g0 = xr[1], g1 = xr[2], g2 = xr[3], g3 = xr[4];

    // ---- my half's 8 neighbor coords (32 VGPRs) ----
    const float* nbase = xr + 1 + SDIM + half * (NNB_H * SDIM);
    float e0[NNB_H], e1[NNB_H], e2[NNB_H], e3[NNB_H];
    #pragma unroll
    for (int n = 0; n < NNB_H; ++n) {
        e0[n] = nbase[n*SDIM + 0];
        e1[n] = nbase[n*SDIM + 1];
        e2[n] = nbase[n*SDIM + 2];
        e3[n] = nbase[n*SDIM + 3];
    }
    // ---- my half's 4 obstacle coords ----
    const float* obase = xr + 1 + SDIM + SDIM*NNB + half * (NOB_H * 2);
    float o0[NOB_H], o1[NOB_H];
    #pragma unroll
    for (int n = 0; n < NOB_H; ++n) {
        o0[n] = obase[n*2 + 0];
        o1[n] = obase[n*2 + 1];
    }

    // ---- barrier partial sums for my half ----
    float barx = 0.f, bary = 0.f;
    #pragma unroll
    for (int n = 0; n < NNB_H; ++n) {
        float px = -e0[n], py = -e1[n];
        float nrm = fast_sqrt(px*px + py*py);
        float coef = 0.05f * fast_rcp(nrm * (nrm - 0.3f));
        barx += coef * px;
        bary += coef * py;
    }
    #pragma unroll
    for (int n = 0; n < NOB_H; ++n) {
        float px = -o0[n], py = -o1[n];
        float nrm = fast_sqrt(px*px + py*py);
        float coef = 0.05f * fast_rcp(nrm * (nrm - 0.3f));
        barx += coef * px;
        bary += coef * py;
    }

    // ---------------- neighbor deepset phi (my 8), k-outer ------------------
    float phin[ED];
    #pragma unroll
    for (int j = 0; j < ED; ++j) phin[j] = 0.f;

    for (int k = 0; k < H1D; ++k) {
        float w0 = Wp1n[0*H1D + k], w1 = Wp1n[1*H1D + k];
        float w2 = Wp1n[2*H1D + k], w3 = Wp1n[3*H1D + k];
        float bk = bp1n[k];
        float h[NNB_H];
        #pragma unroll
        for (int n = 0; n < NNB_H; ++n) {
            float v = bk + e0[n]*w0 + e1[n]*w1 + e2[n]*w2 + e3[n]*w3;
            h[n] = fmaxf(v, 0.f);
        }
        const float* w2p = Wp2n + k*ED;
        #pragma unroll
        for (int j = 0; j < ED; ++j) {
            float wj = w2p[j];
            float s = phin[j];
            #pragma unroll
            for (int n = 0; n < NNB_H; ++n) s += h[n] * wj;
            phin[j] = s;
        }
    }
    #pragma unroll
    for (int j = 0; j < ED; ++j) phin[j] += (float)NNB_H * bp2n[j];

    // ---------------- obstacle deepset phi (my 4) ---------------------------
    float phio[ED];
    #pragma unroll
    for (int j = 0; j < ED; ++j) phio[j] = 0.f;

    for (int k = 0; k < H1D; ++k) {
        float w0 = Wp1o[0*H1D + k], w1 = Wp1o[1*H1D + k];
        float bk = bp1o[k];
        float h[NOB_H];
        #pragma unroll
        for (int n = 0; n < NOB_H; ++n) {
            float v = bk + o0[n]*w0 + o1[n]*w1;
            h[n] = fmaxf(v, 0.f);
        }
        const float* w2p = Wp2o + k*ED;
        #pragma unroll
        for (int j = 0; j < ED; ++j) {
            float wj = w2p[j];
            float s = phio[j];
            #pragma unroll
            for (int n = 0; n < NOB_H; ++n) s += h[n] * wj;
            phio[j] = s;
        }
    }
    #pragma unroll
    for (int j = 0; j < ED; ++j) phio[j] += (float)NOB_H * bp2o[j];

    // ---------------- combine the two halves (lane^1) -----------------------
    #pragma unroll
    for (int j = 0; j < ED; ++j) phin[j] += __shfl_xor(phin[j], 1);
    #pragma unroll
    for (int j = 0; j < ED; ++j) phio[j] += __shfl_xor(phio[j], 1);
    barx += __shfl_xor(barx, 1);
    bary += __shfl_xor(bary, 1);

    // ---------------- rho_n = mlp2(phin)  (duplicated tail) -----------------
    float rhon[ED];
    #pragma unroll
    for (int j = 0; j < ED; ++j) rhon[j] = br2n[j];
    #pragma unroll 2
    for (int k = 0; k < H1D; ++k) {
        float s0 = br1n[k], s1 = 0.f, s2 = 0.f, s3 = 0.f;
        #pragma unroll
        for (int j = 0; j < ED; j += 4) {
            s0 += phin[j+0] * Wr1n[(j+0)*H1D + k];
            s1 += phin[j+1] * Wr1n[(j+1)*H1D + k];
            s2 += phin[j+2] * Wr1n[(j+2)*H1D + k];
            s3 += phin[j+3] * Wr1n[(j+3)*H1D + k];
        }
        float h = fmaxf((s0 + s1) + (s2 + s3), 0.f);
        const float* w2p = Wr2n + k*ED;
        #pragma unroll
        for (int j = 0; j < ED; ++j) rhon[j] += h * w2p[j];
    }

    // ---------------- rho_o = mlp2(phio) ------------------------------------
    float rhoo[ED];
    #pragma unroll
    for (int j = 0; j < ED; ++j) rhoo[j] = br2o[j];
    #pragma unroll 2
    for (int k = 0; k < H1D; ++k) {
        float s0 = br1o[k], s1 = 0.f, s2 = 0.f, s3 = 0.f;
        #pragma unroll
        for (int j = 0; j < ED; j += 4) {
            s0 += phio[j+0] * Wr1o[(j+0)*H1D + k];
            s1 += phio[j+1] * Wr1o[(j+1)*H1D + k];
            s2 += phio[j+2] * Wr1o[(j+2)*H1D + k];
            s3 += phio[j+3] * Wr1o[(j+3)*H1D + k];
        }
        float h = fmaxf((s0 + s1) + (s2 + s3), 0.f);
        const float* w2p = Wr2o + k*ED;
        #pragma unroll
        for (int j = 0; j < ED; ++j) rhoo[j] += h * w2p[j];
    }

    // ---------------- psi head: h = [rho_n, rho_o, g] (36) ------------------
    float a0 = bpsi2[0], a1 = bpsi2[1];
    #pragma unroll 2
    for (int k = 0; k < HPD; ++k) {
        float s0 = bpsi1[k], s1 = 0.f, s2 = 0.f, s3 = 0.f;
        #pragma unroll
        for (int j = 0; j < ED; j += 4) {
            s0 += rhon[j+0] * Wpsi1[(j+0)*HPD + k];
            s1 += rhon[j+1] * Wpsi1[(j+1)*HPD + k];
            s2 += rhon[j+2] * Wpsi1[(j+2)*HPD + k];
            s3 += rhon[j+3] * Wpsi1[(j+3)*HPD + k];
        }
        #pragma unroll
        for (int j = 0; j < ED; j += 4) {
            s0 += rhoo[j+0] * Wpsi1[(ED+j+0)*HPD + k];
            s1 += rhoo[j+1] * Wpsi1[(ED+j+1)*HPD + k];
            s2 += rhoo[j+2] * Wpsi1[(ED+j+2)*HPD + k];
            s3 += rhoo[j+3] * Wpsi1[(ED+j+3)*HPD + k];
        }
        s0 += g0 * Wpsi1[(2*ED + 0)*HPD + k];
        s1 += g1 * Wpsi1[(2*ED + 1)*HPD + k];
        s2 += g2 * Wpsi1[(2*ED + 2)*HPD + k];
        s3 += g3 * Wpsi1[(2*ED + 3)*HPD + k];
        float h = fmaxf((s0 + s1) + (s2 + s3), 0.f);
        a0 += h * Wpsi2[k*2 + 0];
        a1 += h * Wpsi2[k*2 + 1];
    }

    // emp = 2*tanh(a); action = emp + barrier; normalize
    a0 = two_tanh(a0) + barx;
    a1 = two_tanh(a1) + bary;
    float amax = fmaxf(fabsf(a0), fabsf(a1));
    float inv_alpha = fmaxf(amax * 0.5f, 1.0f);  // A_MAX = 2.0
    float r = fast_rcp(inv_alpha);

    // each half writes its own component -> fully coalesced dword stores
    float my = (half == 0) ? a0 * r : a1 * r;
    out[(size_t)row*2 + half] = my;
}

extern "C" void kernel_launch(void* const* d_in, const int* in_sizes, int n_in,
                              void* d_out, int out_size, void* d_ws, size_t ws_size,
                              hipStream_t stream) {
    const float* x     = (const float*)d_in[0];
    const float* Wp1n  = (const float*)d_in[1];
    const float* bp1n  = (const float*)d_in[2];
    const float* Wp2n  = (const float*)d_in[3];
    const float* bp2n  = (const float*)d_in[4];
    const float* Wr1n  = (const float*)d_in[5];
    const float* br1n  = (const float*)d_in[6];
    const float* Wr2n  = (const float*)d_in[7];
    const float* br2n  = (const float*)d_in[8];
    const float* Wp1o  = (const float*)d_in[9];
    const float* bp1o  = (const float*)d_in[10];
    const float* Wp2o  = (const float*)d_in[11];
    const float* bp2o  = (const float*)d_in[12];
    const float* Wr1o  = (const float*)d_in[13];
    const float* br1o  = (const float*)d_in[14];
    const float* Wr2o  = (const float*)d_in[15];
    const float* br2o  = (const float*)d_in[16];
    const float* Wpsi1 = (const float*)d_in[17];
    const float* bpsi1 = (const float*)d_in[18];
    const float* Wpsi2 = (const float*)d_in[19];
    const float* bpsi2 = (const float*)d_in[20];
    float* out = (float*)d_out;

    int nb = in_sizes[0] / XW;   // 131072
    int nthreads = nb * 2;       // 2 threads per row
    int block = 256;
    int grid = (nthreads + block - 1) / block;
    barrier_net_kernel<<<grid, block, 0, stream>>>(
        x, Wp1n, bp1n, Wp2n, bp2n, Wr1n, br1n, Wr2n, br2n,
        Wp1o, bp1o, Wp2o, bp2o, Wr1o, br1o, Wr2o, br2o,
        Wpsi1, bpsi1, Wpsi2, bpsi2, out, nb);
}

// Round 4
// 200.148 us; speedup vs baseline: 1.3301x; 1.3301x over previous
//
#include <hip/hip_runtime.h>
#include <math.h>

// Problem constants (from reference)
#define NNB 16   // neighbors
#define NOB 8    // obstacles
#define SDIM 4   // state dim
#define H1D 64   // hidden 1
#define ED 16    // embedding
#define HPD 64   // psi hidden
#define XW (1 + SDIM + SDIM*NNB + 2*NOB)  // 85 floats per row

__device__ __forceinline__ float fast_rcp(float x) { return __builtin_amdgcn_rcpf(x); }
__device__ __forceinline__ float fast_sqrt(float x) { return __builtin_amdgcn_sqrtf(x); }

// 2*tanh(a), overflow-safe, ~1e-6 rel err (output compared at bf16 granularity)
__device__ __forceinline__ float two_tanh(float a) {
    float ax = fabsf(a);
    float e = __expf(2.0f * ax);
    float t = 1.0f - 2.0f * fast_rcp(e + 1.0f);
    return copysignf(2.0f * t, a);
}

// KEY IDENTITY: phi.sum(over set) commutes with the second (linear) matmul:
//   phi[j] = sum_n [ relu(e_n@W1+b1) @ W2 + b2 ]_j
//          = sum_k ( sum_n relu(e_n . W1[:,k] + b1[k]) ) * W2[k,j] + N*b2[j]
// -> stage-2 cost drops 16x (neighbors) / 8x (obstacles).
__global__ __launch_bounds__(256, 2) void barrier_net_kernel(
    const float* __restrict__ x,
    const float* __restrict__ Wp1n, const float* __restrict__ bp1n,
    const float* __restrict__ Wp2n, const float* __restrict__ bp2n,
    const float* __restrict__ Wr1n, const float* __restrict__ br1n,
    const float* __restrict__ Wr2n, const float* __restrict__ br2n,
    const float* __restrict__ Wp1o, const float* __restrict__ bp1o,
    const float* __restrict__ Wp2o, const float* __restrict__ bp2o,
    const float* __restrict__ Wr1o, const float* __restrict__ br1o,
    const float* __restrict__ Wr2o, const float* __restrict__ br2o,
    const float* __restrict__ Wpsi1, const float* __restrict__ bpsi1,
    const float* __restrict__ Wpsi2, const float* __restrict__ bpsi2,
    float* __restrict__ out, int nb)
{
    int row = blockIdx.x * blockDim.x + threadIdx.x;
    if (row >= nb) return;
    const float* xr = x + (size_t)row * XW;

    // goal vector
    float g0 = xr[1], g1 = xr[2], g2 = xr[3], g3 = xr[4];

    // ---- all neighbor coords in registers ----
    float e0[NNB], e1[NNB], e2[NNB], e3[NNB];
    #pragma unroll
    for (int n = 0; n < NNB; ++n) {
        e0[n] = xr[1 + SDIM + n*SDIM + 0];
        e1[n] = xr[1 + SDIM + n*SDIM + 1];
        e2[n] = xr[1 + SDIM + n*SDIM + 2];
        e3[n] = xr[1 + SDIM + n*SDIM + 3];
    }
    // ---- obstacle coords ----
    const int obs_off = 1 + SDIM + SDIM*NNB;  // 69
    float o0[NOB], o1[NOB];
    #pragma unroll
    for (int n = 0; n < NOB; ++n) {
        o0[n] = xr[obs_off + n*2 + 0];
        o1[n] = xr[obs_off + n*2 + 1];
    }

    // ---- barrier sums (fast rcp/sqrt: ~1ulp, invisible at bf16 compare) ----
    float barx = 0.f, bary = 0.f;
    #pragma unroll
    for (int n = 0; n < NNB; ++n) {
        float px = -e0[n], py = -e1[n];
        float nrm = fast_sqrt(px*px + py*py);
        float coef = 0.05f * fast_rcp(nrm * (nrm - 0.3f));
        barx += coef * px;
        bary += coef * py;
    }
    #pragma unroll
    for (int n = 0; n < NOB; ++n) {
        float px = -o0[n], py = -o1[n];
        float nrm = fast_sqrt(px*px + py*py);
        float coef = 0.05f * fast_rcp(nrm * (nrm - 0.3f));
        barx += coef * px;
        bary += coef * py;
    }

    // ---------------- merged phi loop (neighbors + obstacles) ---------------
    float phin[ED], phio[ED];
    #pragma unroll
    for (int j = 0; j < ED; ++j) { phin[j] = 0.f; phio[j] = 0.f; }

    #pragma unroll 2
    for (int k = 0; k < H1D; ++k) {
        // ---- neighbor hidden-sum: sn = sum_n relu(e_n . W1n[:,k] + b1n[k])
        float wn0 = Wp1n[0*H1D + k], wn1 = Wp1n[1*H1D + k];
        float wn2 = Wp1n[2*H1D + k], wn3 = Wp1n[3*H1D + k];
        float bn  = bp1n[k];
        float hn[NNB];
        #pragma unroll
        for (int n = 0; n < NNB; ++n) {
            float v = fmaf(e3[n], wn3, fmaf(e2[n], wn2, fmaf(e1[n], wn1, fmaf(e0[n], wn0, bn))));
            hn[n] = fmaxf(v, 0.f);
        }
        // tree reduce 16 -> 1 (log depth for ILP)
        #pragma unroll
        for (int s = NNB/2; s > 0; s >>= 1)
            #pragma unroll
            for (int n = 0; n < s; ++n) hn[n] += hn[n+s];
        float sn = hn[0];

        // ---- obstacle hidden-sum
        float wo0 = Wp1o[0*H1D + k], wo1 = Wp1o[1*H1D + k];
        float bo  = bp1o[k];
        float ho[NOB];
        #pragma unroll
        for (int n = 0; n < NOB; ++n) {
            float v = fmaf(o1[n], wo1, fmaf(o0[n], wo0, bo));
            ho[n] = fmaxf(v, 0.f);
        }
        #pragma unroll
        for (int s = NOB/2; s > 0; s >>= 1)
            #pragma unroll
            for (int n = 0; n < s; ++n) ho[n] += ho[n+s];
        float so = ho[0];

        // ---- scatter into phi accumulators: phi[j] += s * W2[k,j]
        const float* w2n = Wp2n + k*ED;
        const float* w2o = Wp2o + k*ED;
        #pragma unroll
        for (int j = 0; j < ED; ++j) {
            phin[j] = fmaf(sn, w2n[j], phin[j]);
            phio[j] = fmaf(so, w2o[j], phio[j]);
        }
    }
    #pragma unroll
    for (int j = 0; j < ED; ++j) {
        phin[j] = fmaf((float)NNB, bp2n[j], phin[j]);
        phio[j] = fmaf((float)NOB, bp2o[j], phio[j]);
    }

    // ---------------- rho_n / rho_o merged k-loop ---------------------------
    float rhon[ED], rhoo[ED];
    #pragma unroll
    for (int j = 0; j < ED; ++j) { rhon[j] = br2n[j]; rhoo[j] = br2o[j]; }

    #pragma unroll 2
    for (int k = 0; k < H1D; ++k) {
        float sn0 = br1n[k], sn1 = 0.f, sn2 = 0.f, sn3 = 0.f;
        float so0 = br1o[k], so1 = 0.f, so2 = 0.f, so3 = 0.f;
        #pragma unroll
        for (int j = 0; j < ED; j += 4) {
            sn0 = fmaf(phin[j+0], Wr1n[(j+0)*H1D + k], sn0);
            sn1 = fmaf(phin[j+1], Wr1n[(j+1)*H1D + k], sn1);
            sn2 = fmaf(phin[j+2], Wr1n[(j+2)*H1D + k], sn2);
            sn3 = fmaf(phin[j+3], Wr1n[(j+3)*H1D + k], sn3);
            so0 = fmaf(phio[j+0], Wr1o[(j+0)*H1D + k], so0);
            so1 = fmaf(phio[j+1], Wr1o[(j+1)*H1D + k], so1);
            so2 = fmaf(phio[j+2], Wr1o[(j+2)*H1D + k], so2);
            so3 = fmaf(phio[j+3], Wr1o[(j+3)*H1D + k], so3);
        }
        float hn = fmaxf((sn0 + sn1) + (sn2 + sn3), 0.f);
        float ho = fmaxf((so0 + so1) + (so2 + so3), 0.f);
        const float* w2n = Wr2n + k*ED;
        const float* w2o = Wr2o + k*ED;
        #pragma unroll
        for (int j = 0; j < ED; ++j) {
            rhon[j] = fmaf(hn, w2n[j], rhon[j]);
            rhoo[j] = fmaf(ho, w2o[j], rhoo[j]);
        }
    }

    // ---------------- psi head: h = [rho_n, rho_o, g] (36) ------------------
    float a0 = bpsi2[0], a1 = bpsi2[1];
    #pragma unroll 2
    for (int k = 0; k < HPD; ++k) {
        float s0 = bpsi1[k], s1 = 0.f, s2 = 0.f, s3 = 0.f;
        #pragma unroll
        for (int j = 0; j < ED; j += 4) {
            s0 = fmaf(rhon[j+0], Wpsi1[(j+0)*HPD + k], s0);
            s1 = fmaf(rhon[j+1], Wpsi1[(j+1)*HPD + k], s1);
            s2 = fmaf(rhon[j+2], Wpsi1[(j+2)*HPD + k], s2);
            s3 = fmaf(rhon[j+3], Wpsi1[(j+3)*HPD + k], s3);
        }
        #pragma unroll
        for (int j = 0; j < ED; j += 4) {
            s0 = fmaf(rhoo[j+0], Wpsi1[(ED+j+0)*HPD + k], s0);
            s1 = fmaf(rhoo[j+1], Wpsi1[(ED+j+1)*HPD + k], s1);
            s2 = fmaf(rhoo[j+2], Wpsi1[(ED+j+2)*HPD + k], s2);
            s3 = fmaf(rhoo[j+3], Wpsi1[(ED+j+3)*HPD + k], s3);
        }
        s0 = fmaf(g0, Wpsi1[(2*ED + 0)*HPD + k], s0);
        s1 = fmaf(g1, Wpsi1[(2*ED + 1)*HPD + k], s1);
        s2 = fmaf(g2, Wpsi1[(2*ED + 2)*HPD + k], s2);
        s3 = fmaf(g3, Wpsi1[(2*ED + 3)*HPD + k], s3);
        float h = fmaxf((s0 + s1) + (s2 + s3), 0.f);
        a0 = fmaf(h, Wpsi2[k*2 + 0], a0);
        a1 = fmaf(h, Wpsi2[k*2 + 1], a1);
    }

    // emp = 2*tanh(a); action = emp + barrier; normalize
    a0 = two_tanh(a0) + barx;
    a1 = two_tanh(a1) + bary;
    float amax = fmaxf(fabsf(a0), fabsf(a1));
    float inv_alpha = fmaxf(amax * 0.5f, 1.0f);  // A_MAX = 2.0
    float r = fast_rcp(inv_alpha);

    out[(size_t)row*2 + 0] = a0 * r;
    out[(size_t)row*2 + 1] = a1 * r;
}

extern "C" void kernel_launch(void* const* d_in, const int* in_sizes, int n_in,
                              void* d_out, int out_size, void* d_ws, size_t ws_size,
                              hipStream_t stream) {
    const float* x     = (const float*)d_in[0];
    const float* Wp1n  = (const float*)d_in[1];
    const float* bp1n  = (const float*)d_in[2];
    const float* Wp2n  = (const float*)d_in[3];
    const float* bp2n  = (const float*)d_in[4];
    const float* Wr1n  = (const float*)d_in[5];
    const float* br1n  = (const float*)d_in[6];
    const float* Wr2n  = (const float*)d_in[7];
    const float* br2n  = (const float*)d_in[8];
    const float* Wp1o  = (const float*)d_in[9];
    const float* bp1o  = (const float*)d_in[10];
    const float* Wp2o  = (const float*)d_in[11];
    const float* bp2o  = (const float*)d_in[12];
    const float* Wr1o  = (const float*)d_in[13];
    const float* br1o  = (const float*)d_in[14];
    const float* Wr2o  = (const float*)d_in[15];
    const float* br2o  = (const float*)d_in[16];
    const float* Wpsi1 = (const float*)d_in[17];
    const float* bpsi1 = (const float*)d_in[18];
    const float* Wpsi2 = (const float*)d_in[19];
    const float* bpsi2 = (const float*)d_in[20];
    float* out = (float*)d_out;

    int nb = in_sizes[0] / XW;   // 131072
    int block = 256;
    int grid = (nb + block - 1) / block;
    barrier_net_kernel<<<grid, block, 0, stream>>>(
        x, Wp1n, bp1n, Wp2n, bp2n, Wr1n, br1n, Wr2n, br2n,
        Wp1o, bp1o, Wp2o, bp2o, Wr1o, br1o, Wr2o, br2o,
        Wpsi1, bpsi1, Wpsi2, bpsi2, out, nb);
}